// Round 13
// baseline (1343.602 us; speedup 1.0000x reference)
//
#include <hip/hip_runtime.h>

#define NN 50000
#define NE 800000
#define DBINS 1024

typedef __attribute__((ext_vector_type(8))) short bf16x8;
typedef __attribute__((ext_vector_type(4))) float f32x4;
typedef __attribute__((ext_vector_type(16))) float f32x16;

__device__ __forceinline__ unsigned short f2bf(float f) {
    union { float f; unsigned u; } v; v.f = f;
    unsigned r = v.u + 0x7FFFu + ((v.u >> 16) & 1u);
    return (unsigned short)(r >> 16);
}

// 32-bit-offset gather (uniform 64-bit base + 32-bit voffset)
__device__ __forceinline__ int4 ld_ep1(const int4* ep, unsigned idx) {
    return *(const int4*)((const char*)ep + (size_t)(idx * 16u));
}

// bf16 LDS A-fragment layout (16 nodes):
//   element (kstep kk, r = k&31, node m) at ushort index
//   kk*544 + (r>>3)*136 + m*8 + (r&7)
__device__ __forceinline__ int us_idx(int kk, int r, int m) {
    return kk*544 + (r >> 3)*136 + m*8 + (r & 7);
}

// ---------------- stage-1: edge aggregation as 32x32x16 MFMA ----------------
// One node per call (full wave). h[wi][ch] = sum_e w(e)[wi] * X[src(e)][ch].
// A[wi=lane&31][k=(lane>>5)*8+j] computed ON THE FLY from (v0,v1):
//   w[wi] = hat(v0, wi%5) * hat(v1, wi/5)  (wi<25), 1.0 (wi==25), 0 (else).
// B[ch=nt*32+(lane&31)][k] = Xh[src(e(k))*CIN + ch].
// D: col=lane&31, row=(reg&3)+8*(reg>>2)+4*(lane>>5)  [HW-verified m74/m101].
// ep = (src, v0f, v1f, 0); pad slots carry v=1e9 -> w=0 (ones-row lane hits
// the zero feature row); k>=degp tail zeroed via the (k<degp) mask.
template<int CIN, int NT2>
__device__ __forceinline__ void stage1_node32(
        const int4* __restrict__ ep,
        const unsigned short* __restrict__ Xh,
        int ebeg, int degp, int lane,
        float r0, float r1, int wsel,
        f32x16 (&d)[NT2]) {
#pragma unroll
    for (int nt = 0; nt < NT2; ++nt)
#pragma unroll
        for (int r = 0; r < 16; ++r) d[nt][r] = 0.f;
    if (degp <= 0) return;
    const int m = lane & 31;
    const int kb = (lane >> 5) * 8;
    const int last = degp - 1;
    for (int k0 = 0; k0 < degp; k0 += 16) {
        int s[8];
        union { unsigned short us[8]; bf16x8 v; } a;
#pragma unroll
        for (int j = 0; j < 8; ++j) {
            int k = k0 + kb + j;
            int4 P = ld_ep1(ep, (unsigned)(ebeg + min(k, last)));
            s[j] = P.x;
            float v0 = __int_as_float(P.y), v1 = __int_as_float(P.z);
            float wxa = fmaxf(1.f - fabsf(v0 - r0), 0.f);
            float wya = fmaxf(1.f - fabsf(v1 - r1), 0.f);
            float wv = (wsel == 0) ? wxa * wya : ((wsel == 1) ? 1.f : 0.f);
            a.us[j] = (k < degp) ? f2bf(wv) : (unsigned short)0;
        }
#pragma unroll
        for (int nt = 0; nt < NT2; ++nt) {
            union { unsigned short us[8]; bf16x8 v; } b;
#pragma unroll
            for (int j = 0; j < 8; ++j)
                b.us[j] = Xh[(size_t)s[j]*CIN + nt*32 + m];
            d[nt] = __builtin_amdgcn_mfma_f32_32x32x16_bf16(a.v, b.v, d[nt], 0, 0, 0);
        }
    }
}

// ---------------- setup kernels ----------------
__global__ __launch_bounds__(256) void k_zero(int* degi, int* cur, float* stats,
                                              int* dcnt, int* dcur,
                                              unsigned* xz, unsigned* hz) {
    int i = blockIdx.x*256 + threadIdx.x;
    int stride = gridDim.x*256;
    for (int j = i; j < NN; j += stride) { degi[j] = 0; cur[j] = 0; }
    if (i < 384) stats[i] = 0.f;
    if (i < DBINS) { dcnt[i] = 0; dcur[i] = 0; }
    if (i < 16) xz[i] = 0u;
    if (i < 32) hz[i] = 0u;
}

__global__ __launch_bounds__(256) void k_hist(const int* __restrict__ dst, int* degi) {
    int e = blockIdx.x*256 + threadIdx.x;
    if (e < NE) atomicAdd(&degi[dst[e]], 1);
}

// scan of CEIL4(deg) -> padded offsets
__global__ __launch_bounds__(256) void k_scan_block(const int* __restrict__ degi,
                                                    int* off, int* bsum) {
    __shared__ int sh[256];
    int t = threadIdx.x;
    int base = blockIdx.x * 1024;
    int v[4]; int s = 0;
#pragma unroll
    for (int j = 0; j < 4; j++) {
        int idx = base + t*4 + j;
        v[j] = (idx < NN) ? ((degi[idx] + 3) & ~3) : 0;
        s += v[j];
    }
    sh[t] = s; __syncthreads();
    for (int ofs = 1; ofs < 256; ofs <<= 1) {
        int x = (t >= ofs) ? sh[t - ofs] : 0;
        __syncthreads();
        sh[t] += x;
        __syncthreads();
    }
    int ex = sh[t] - s;
#pragma unroll
    for (int j = 0; j < 4; j++) {
        int idx = base + t*4 + j;
        if (idx < NN) off[idx] = ex;
        ex += v[j];
    }
    if (t == 255) bsum[blockIdx.x] = sh[255];
}

__global__ __launch_bounds__(256) void k_dhist(const int* __restrict__ degi, int* dcnt) {
    __shared__ int lh[DBINS];
    int t = threadIdx.x;
#pragma unroll
    for (int j = 0; j < DBINS/256; ++j) lh[t + 256*j] = 0;
    __syncthreads();
    int n = blockIdx.x*256 + t;
    if (n < NN) atomicAdd(&lh[min(degi[n], DBINS-1)], 1);
    __syncthreads();
#pragma unroll
    for (int j = 0; j < DBINS/256; ++j) {
        int b = t + 256*j;
        if (lh[b]) atomicAdd(&dcnt[b], lh[b]);
    }
}

// fused: block 0 = top-level scan of bsum; block 1 = 1024-bin degree scan
__global__ __launch_bounds__(256) void k_topscan(const int* __restrict__ bsum,
                                                 int* bpre, int nb,
                                                 const int* __restrict__ dcnt,
                                                 int* dbase) {
    __shared__ int sh[256];
    int t = threadIdx.x;
    if (blockIdx.x == 0) {
        int s = (t < nb) ? bsum[t] : 0;
        sh[t] = s; __syncthreads();
        for (int ofs = 1; ofs < 256; ofs <<= 1) {
            int x = (t >= ofs) ? sh[t - ofs] : 0;
            __syncthreads();
            sh[t] += x;
            __syncthreads();
        }
        if (t < nb) bpre[t] = sh[t] - s;
    } else {
        int v[4]; int s = 0;
#pragma unroll
        for (int j = 0; j < 4; j++) { v[j] = dcnt[t*4 + j]; s += v[j]; }
        sh[t] = s; __syncthreads();
        for (int ofs = 1; ofs < 256; ofs <<= 1) {
            int x = (t >= ofs) ? sh[t - ofs] : 0;
            __syncthreads();
            sh[t] += x;
            __syncthreads();
        }
        int ex = sh[t] - s;
#pragma unroll
        for (int j = 0; j < 4; j++) { dbase[t*4 + j] = ex; ex += v[j]; }
    }
}

__global__ __launch_bounds__(256) void k_scan_add(int* off, const int* __restrict__ bpre,
                                                  const int* __restrict__ degi) {
    int i = blockIdx.x*256 + threadIdx.x;
    if (i < NN) {
        int v = off[i] + bpre[i >> 10];
        off[i] = v;
        if (i == NN - 1) off[NN] = v + ((degi[i] + 3) & ~3);
    }
}

// fused: counting-sort scatter (LDS-staged) + pad fill (src=NN, v=1e9 -> w=0)
__global__ __launch_bounds__(256) void k_pscatter_pad(const int* __restrict__ degi,
                                                      const int* __restrict__ dbase,
                                                      int* dcur, int* perm,
                                                      const int* __restrict__ off,
                                                      int4* __restrict__ ep) {
    __shared__ int lh[DBINS];
    __shared__ int lb[DBINS];
    int t = threadIdx.x;
#pragma unroll
    for (int j = 0; j < DBINS/256; ++j) lh[t + 256*j] = 0;
    __syncthreads();
    int n = blockIdx.x*256 + t;
    int d = 0, lr = 0;
    bool act = (n < NN);
    if (act) {
        d = min(degi[n], DBINS-1);
        lr = atomicAdd(&lh[d], 1);
    }
    __syncthreads();
#pragma unroll
    for (int j = 0; j < DBINS/256; ++j) {
        int b = t + 256*j;
        int c = lh[b];
        lb[b] = c ? atomicAdd(&dcur[b], c) : 0;
    }
    __syncthreads();
    if (act) {
        perm[dbase[d] + lb[d] + lr] = n;
        int base = off[n] + degi[n];
        int end  = off[n + 1];
        for (int p = base; p < end; ++p)
            ep[p] = make_int4(NN, __float_as_int(1e9f), __float_as_int(1e9f), 0);
    }
}

// per edge: ep[p] = (src, v0, v1, 0) with v = pseudo*4 in [0,4).
__global__ __launch_bounds__(256) void k_scatter(const int* __restrict__ src,
                                                 const int* __restrict__ dst,
                                                 const float* __restrict__ ea,
                                                 const int* __restrict__ off, int* cur,
                                                 int4* __restrict__ ep) {
    int e = blockIdx.x*256 + threadIdx.x;
    if (e >= NE) return;
    int d = dst[e];
    int p = off[d] + atomicAdd(&cur[d], 1);
    float v0 = ea[2*e]     * 4.f;
    float v1 = ea[2*e + 1] * 4.f;
    ep[p] = make_int4(src[e], __float_as_int(v0), __float_as_int(v1), 0);
}

__device__ __forceinline__ void wprep_body(int tid, const float* W, const float* root,
                                           int KTC, unsigned short* Wb) {
    int lane = tid & 63, cot = (tid >> 6) & 3, kk = tid >> 8;
    int co = 16*cot + (lane & 15);
    int kbase = kk*32 + ((lane >> 4) * 8);
    union { unsigned short s[8]; uint4 v; } u;
#pragma unroll
    for (int j = 0; j < 8; j++) {
        int k = kbase + j;
        float val = (k < KTC) ? W[(size_t)k*64 + co] : root[(size_t)(k - KTC)*64 + co];
        u.s[j] = f2bf(val);
    }
    *(uint4*)(Wb + (size_t)tid * 8) = u.v;
}

// fused prep: x->bf16 (blocks 0..1562) + 3x weight tiling
__global__ __launch_bounds__(256) void k_prep(const float* __restrict__ x,
                                              unsigned short* __restrict__ xb,
                                              const float* __restrict__ w1,
                                              const float* __restrict__ r1,
                                              unsigned short* Wb1,
                                              const float* __restrict__ wsN,
                                              const float* __restrict__ rs,
                                              unsigned short* WbS,
                                              const float* __restrict__ w2,
                                              const float* __restrict__ r2,
                                              unsigned short* Wb2) {
    int b = blockIdx.x, t = threadIdx.x;
    if (b < 1563) {
        int i = b*256 + t;
        if (i >= NN*8) return;
        float4 v = ((const float4*)x)[i];
        uint2 pk;
        pk.x = (unsigned)f2bf(v.x) | ((unsigned)f2bf(v.y) << 16);
        pk.y = (unsigned)f2bf(v.z) | ((unsigned)f2bf(v.w) << 16);
        ((uint2*)xb)[i] = pk;
    } else if (b < 1589) {
        wprep_body((b - 1563)*256 + t, w1, r1, 800, Wb1);
    } else if (b < 1591) {
        wprep_body((b - 1589)*256 + t, wsN, rs, 32, WbS);
    } else {
        wprep_body((b - 1591)*256 + t, w2, r2, 1600, Wb2);
    }
}

// ---------------- conv1 + convS: 16 nodes/block, 32x32 MFMA stage-1 --------
// 8 waves; wave w handles nodes 2w, 2w+1 (CIN=32, one 32-col tile).
// A-tile layout: kk=wi (0..24), kk25=x, kk26=hs(ones row wi==25), kk27=x.
// VGPR pinned <= 64 for 32 waves/CU (LDS 30.5 KB -> 4 blocks).
__global__ __launch_bounds__(512, 8) void k_conv1s(
        const unsigned short* __restrict__ Xh,   // xbf [NN+1][32]
        const int* __restrict__ off,
        const int* __restrict__ degi,
        const int4* __restrict__ ep,
        const int* __restrict__ perm,
        const unsigned short* __restrict__ Wb1,
        const unsigned short* __restrict__ WbS,
        const float* __restrict__ b1,
        const float* __restrict__ bs,
        float* __restrict__ agg1,
        float* __restrict__ aggS) {
    __shared__ __align__(16) unsigned short hb[28*544];  // 30.5 KB
    unsigned* hb32 = (unsigned*)hb;
    const int t = threadIdx.x, lane = t & 63, w = t >> 6;
    const int n0 = NN - 16 - blockIdx.x * 16;   // LPT
    const int m32 = lane & 31;
    const int hh = lane >> 5;
    const float r0 = (float)(m32 % 5), r1 = (float)(m32 / 5);
    const int wsel = (m32 < 25) ? 0 : ((m32 == 25) ? 1 : 2);
    const int basel = (m32 >> 3)*136 + (m32 & 7);

#pragma unroll
    for (int nn = 0; nn < 2; ++nn) {
        const int g = 2*w + nn;
        const int n = perm[n0 + g];
        const int deg = degi[n];
        const int degp = (deg + 3) & ~3;
        f32x16 d[1];
        stage1_node32<32, 1>(ep, Xh, off[n], degp, lane, r0, r1, wsel, d);
        const float rdeg = 1.f / (float)max(deg, 1);
#pragma unroll
        for (int reg = 0; reg < 16; ++reg) {
            int wi = (reg & 3) + 8*(reg >> 2) + 4*hh;
            if (wi <= 25) {
                int kk = (wi < 25) ? wi : 26;
                hb[kk*544 + basel + g*8] = f2bf(d[0][reg] * rdeg);
            }
        }
    }
    // x rows (kk 25 and 27): 16 dwords per node
    if ((lane & 31) < 16) {
        const int g2 = 2*w + hh;
        const int cd = lane & 15;
        const int n2 = perm[n0 + g2];
        unsigned xv = ((const unsigned*)Xh)[(size_t)n2*16 + cd];
        const int r0d = 2*cd;
        const int dwb = (r0d >> 3)*68 + g2*4 + ((r0d & 7) >> 1);
        hb32[25*272 + dwb] = xv;
        hb32[27*272 + dwb] = xv;
    }
    __syncthreads();

    // ---- stage 2 (unchanged, verified) ----
    const int m = lane & 15, qq = lane >> 4;
    const int co = (w & 3)*16 + m;
    const int4 pn = ((const int4*)perm)[(n0 >> 2) + qq];
    const int prow[4] = {pn.x, pn.y, pn.z, pn.w};
    if (w < 4) {
        f32x4 acc = {0.f, 0.f, 0.f, 0.f};
        for (int kk = 0; kk < 26; ++kk) {
            bf16x8 av = *(const bf16x8*)&hb[kk*544 + qq*136 + m*8];
            bf16x8 bv = *(const bf16x8*)(Wb1 + (size_t)((kk*4 + w)*64 + lane) * 8);
            acc = __builtin_amdgcn_mfma_f32_16x16x32_bf16(av, bv, acc, 0, 0, 0);
        }
        const float bb = b1[co];
#pragma unroll
        for (int r = 0; r < 4; ++r)
            agg1[(size_t)prow[r]*64 + co] = acc[r] + bb;
    } else {
        f32x4 accs = {0.f, 0.f, 0.f, 0.f};
#pragma unroll
        for (int s = 0; s < 2; ++s) {
            bf16x8 av = *(const bf16x8*)&hb[(26 + s)*544 + qq*136 + m*8];
            bf16x8 bv = *(const bf16x8*)(WbS + (size_t)((s*4 + (w & 3))*64 + lane) * 8);
            accs = __builtin_amdgcn_mfma_f32_16x16x32_bf16(av, bv, accs, 0, 0, 0);
        }
        const float bb = bs[co];
#pragma unroll
        for (int r = 0; r < 4; ++r)
            aggS[(size_t)prow[r]*64 + co] = accs[r] + bb;
    }
}

// ---------------- conv2: 16 nodes/block, MFMA stage-1 + K-split LDS -------
// 8 waves; wave w handles nodes 2w, 2w+1 (CIN=64, two 32-col tiles).
// k = wi*64 + ch -> kk = 2wi+nt (0..49), x rows kk 50,51. LDS holds 26 kk
// (27.6 KB -> 4 blocks/CU). Part-1 rows (wi<=12 -> kk 0..25) dump straight
// from d; only regs 5..12 (all wi 13..24) are kept packed (8 dwords/node)
// so peak VGPR stays <= 64 (32 waves/CU).
__global__ __launch_bounds__(512, 8) void k_conv2(
        const unsigned short* __restrict__ Xh,   // h1bf [NN+1][64]
        const int* __restrict__ off,
        const int* __restrict__ degi,
        const int4* __restrict__ ep,
        const int* __restrict__ perm,
        const unsigned short* __restrict__ Wb2,
        const float* __restrict__ b2,
        float* __restrict__ agg) {
    __shared__ __align__(16) unsigned short hb[26*544];  // 27.6 KB
    unsigned* hb32 = (unsigned*)hb;
    const int t = threadIdx.x, lane = t & 63, w = t >> 6;
    const int n0 = NN - 16 - blockIdx.x * 16;   // LPT
    const int m32 = lane & 31;
    const int hh = lane >> 5;
    const float r0 = (float)(m32 % 5), r1 = (float)(m32 / 5);
    const int wsel = (m32 < 25) ? 0 : ((m32 == 25) ? 1 : 2);
    const int basel = (m32 >> 3)*136 + (m32 & 7);

    unsigned pkA[8], pkB[8];   // part-2 keepers: regs 5..12 packed {nt0,nt1}

#pragma unroll
    for (int nn = 0; nn < 2; ++nn) {
        const int g = 2*w + nn;
        const int n = perm[n0 + g];
        const int deg = degi[n];
        const int degp = (deg + 3) & ~3;
        f32x16 d[2];
        stage1_node32<64, 2>(ep, Xh, off[n], degp, lane, r0, r1, wsel, d);
        const float rdeg = 1.f / (float)max(deg, 1);
        // part-1 dump: wi <= 12 -> kk = 2wi, 2wi+1
#pragma unroll
        for (int reg = 0; reg < 16; ++reg) {
            int wi = (reg & 3) + 8*(reg >> 2) + 4*hh;
            if (wi <= 12) {
                hb[(2*wi    )*544 + basel + g*8] = f2bf(d[0][reg] * rdeg);
                hb[(2*wi + 1)*544 + basel + g*8] = f2bf(d[1][reg] * rdeg);
            }
        }
        // pack keepers (regs 5..12 cover all wi in 13..24 across both hh)
        unsigned* pk = nn ? pkB : pkA;
#pragma unroll
        for (int i = 0; i < 8; ++i) {
            int reg = 5 + i;
            pk[i] = (unsigned)f2bf(d[0][reg] * rdeg)
                  | ((unsigned)f2bf(d[1][reg] * rdeg) << 16);
        }
    }
    __syncthreads();

    const int m = lane & 15, qq = lane >> 4;
    f32x4 acc = {0.f, 0.f, 0.f, 0.f};
    if (w < 4) {
        for (int kk = 0; kk < 26; ++kk) {
            bf16x8 av = *(const bf16x8*)&hb[kk*544 + qq*136 + m*8];
            bf16x8 bv = *(const bf16x8*)(Wb2 + (size_t)((kk*4 + w)*64 + lane) * 8);
            acc = __builtin_amdgcn_mfma_f32_16x16x32_bf16(av, bv, acc, 0, 0, 0);
        }
    }
    __syncthreads();

    // part-2 dump: wi 13..24 -> local kk' = 2wi-26, 2wi-25; x rows kk' 24,25
#pragma unroll
    for (int nn = 0; nn < 2; ++nn) {
        const int g = 2*w + nn;
        const unsigned* pk = nn ? pkB : pkA;
#pragma unroll
        for (int i = 0; i < 8; ++i) {
            int reg = 5 + i;
            int wi = (reg & 3) + 8*(reg >> 2) + 4*hh;
            if (wi >= 13 && wi <= 24) {
                hb[(2*wi - 26)*544 + basel + g*8] = (unsigned short)(pk[i] & 0xFFFFu);
                hb[(2*wi - 25)*544 + basel + g*8] = (unsigned short)(pk[i] >> 16);
            }
        }
    }
    {
        const int g2 = 2*w + hh;
        const int c2 = lane & 31;
        const int n2 = perm[n0 + g2];
        unsigned xv = ((const unsigned*)Xh)[(size_t)n2*32 + c2];
        const int r0d = (2*c2) & 31;
        const int dw = (24 + (c2 >> 4))*272 + (r0d >> 3)*68 + g2*4 + ((r0d & 7) >> 1);
        hb32[dw] = xv;
    }
    __syncthreads();

    if (w >= 4) return;
    for (int kk = 0; kk < 26; ++kk) {
        bf16x8 av = *(const bf16x8*)&hb[kk*544 + qq*136 + m*8];
        bf16x8 bv = *(const bf16x8*)(Wb2 + (size_t)(((kk + 26)*4 + w)*64 + lane) * 8);
        acc = __builtin_amdgcn_mfma_f32_16x16x32_bf16(av, bv, acc, 0, 0, 0);
    }
    const int4 pn = ((const int4*)perm)[(n0 >> 2) + qq];
    const int prow[4] = {pn.x, pn.y, pn.z, pn.w};
    const int co = w*16 + m;
    const float bb = b2[co];
#pragma unroll
    for (int rr = 0; rr < 4; ++rr)
        agg[(size_t)prow[rr]*64 + co] = acc[rr] + bb;
}

// ---------------- batch norm ----------------
__global__ __launch_bounds__(256) void k_bnstats(const float* __restrict__ agg, float* stats) {
    __shared__ float sh0[256], sh1[256];
    int t = threadIdx.x;
    float s = 0.f, ss = 0.f;
    int stride = gridDim.x * 256;
    for (int i = blockIdx.x*256 + t; i < NN*64; i += stride) {
        float v = agg[i];
        s += v; ss += v*v;
    }
    sh0[t] = s; sh1[t] = ss;
    __syncthreads();
    if (t < 64) {
        float a = sh0[t] + sh0[t+64] + sh0[t+128] + sh0[t+192];
        float b = sh1[t] + sh1[t+64] + sh1[t+128] + sh1[t+192];
        atomicAdd(&stats[t], a);
        atomicAdd(&stats[64 + t], b);
    }
}

// fused: stats for agg1 (blocks 0..255 -> st2) and aggS (blocks 256..511 -> sts)
__global__ __launch_bounds__(256) void k_bnstats2(const float* __restrict__ a1,
                                                  const float* __restrict__ as,
                                                  float* stats) {
    __shared__ float sh0[256], sh1[256];
    int t = threadIdx.x;
    const float* src = (blockIdx.x < 256) ? a1 : as;
    float* dst = (blockIdx.x < 256) ? (stats + 128) : (stats + 256);
    int bid = (blockIdx.x < 256) ? blockIdx.x : blockIdx.x - 256;
    float s = 0.f, ss = 0.f;
    for (int i = bid*256 + t; i < NN*64; i += 256*256) {
        float v = src[i];
        s += v; ss += v*v;
    }
    sh0[t] = s; sh1[t] = ss;
    __syncthreads();
    if (t < 64) {
        float a = sh0[t] + sh0[t+64] + sh0[t+128] + sh0[t+192];
        float b = sh1[t] + sh1[t+64] + sh1[t+128] + sh1[t+192];
        atomicAdd(&dst[t], a);
        atomicAdd(&dst[64 + t], b);
    }
}

__device__ __forceinline__ float eluf(float u) { return u > 0.f ? u : expm1f(u); }

__global__ __launch_bounds__(256) void k_bn_elu(const float* __restrict__ agg,
                                                const float* __restrict__ stats,
                                                const float* __restrict__ gamma,
                                                const float* __restrict__ beta,
                                                unsigned short* __restrict__ outb) {
    int i = blockIdx.x*256 + threadIdx.x;
    if (i >= NN*16) return;
    float4 v = ((const float4*)agg)[i];
    float r[4] = {v.x, v.y, v.z, v.w};
    int c0 = (i << 2) & 63;
#pragma unroll
    for (int j = 0; j < 4; j++) {
        int c = c0 + j;
        float mu = stats[c] * (1.f/NN);
        float var = stats[64 + c] * (1.f/NN) - mu*mu;
        float sc = gamma[c] * rsqrtf(fmaxf(var, 0.f) + 1e-5f);
        r[j] = eluf((r[j] - mu)*sc + beta[c]);
    }
    uint2 pk;
    pk.x = (unsigned)f2bf(r[0]) | ((unsigned)f2bf(r[1]) << 16);
    pk.y = (unsigned)f2bf(r[2]) | ((unsigned)f2bf(r[3]) << 16);
    ((uint2*)outb)[i] = pk;
}

__global__ __launch_bounds__(256) void k_bn_final(const float* __restrict__ a2,
                                                  const float* __restrict__ st2,
                                                  const float* __restrict__ g2,
                                                  const float* __restrict__ be2,
                                                  const float* __restrict__ as,
                                                  const float* __restrict__ sts,
                                                  const float* __restrict__ gs,
                                                  const float* __restrict__ bes,
                                                  float* __restrict__ out) {
    int i = blockIdx.x*256 + threadIdx.x;
    if (i >= NN*16) return;
    float4 v2 = ((const float4*)a2)[i];
    float4 vs = ((const float4*)as)[i];
    float r2v[4] = {v2.x, v2.y, v2.z, v2.w};
    float rsv[4] = {vs.x, vs.y, vs.z, vs.w};
    float o[4];
    int c0 = (i << 2) & 63;
#pragma unroll
    for (int j = 0; j < 4; j++) {
        int c = c0 + j;
        float mu2 = st2[c] * (1.f/NN);
        float var2 = st2[64 + c] * (1.f/NN) - mu2*mu2;
        float sc2 = g2[c] * rsqrtf(fmaxf(var2, 0.f) + 1e-5f);
        float mus = sts[c] * (1.f/NN);
        float vars = sts[64 + c] * (1.f/NN) - mus*mus;
        float scs = gs[c] * rsqrtf(fmaxf(vars, 0.f) + 1e-5f);
        float u = (r2v[j] - mu2)*sc2 + be2[c] + (rsv[j] - mus)*scs + bes[c];
        o[j] = eluf(u);
    }
    ((float4*)out)[i] = make_float4(o[0], o[1], o[2], o[3]);
}

extern "C" void kernel_launch(void* const* d_in, const int* in_sizes, int n_in,
                              void* d_out, int out_size, void* d_ws, size_t ws_size,
                              hipStream_t stream) {
    const float* x   = (const float*)d_in[0];
    const int*   ei  = (const int*)d_in[1];
    const float* ea  = (const float*)d_in[2];
    const float* w1  = (const float*)d_in[3];
    const float* r1  = (const float*)d_in[4];
    const float* b1  = (const float*)d_in[5];
    const float* g1  = (const float*)d_in[6];
    const float* be1 = (const float*)d_in[7];
    const float* w2  = (const float*)d_in[8];
    const float* r2  = (const float*)d_in[9];
    const float* b2  = (const float*)d_in[10];
    const float* g2  = (const float*)d_in[11];
    const float* be2 = (const float*)d_in[12];
    const float* wsN = (const float*)d_in[13];
    const float* rs  = (const float*)d_in[14];
    const float* bs  = (const float*)d_in[15];
    const float* gs  = (const float*)d_in[16];
    const float* bes = (const float*)d_in[17];
    const int* srcp = ei;
    const int* dstp = ei + NE;

    char* wsb = (char*)d_ws;
    size_t o = 0;
    auto alloc = [&](size_t bytes) -> char* {
        char* p = wsb + o;
        o += (bytes + 255) & ~(size_t)255;
        return p;
    };
    int*    degi    = (int*)   alloc((size_t)NN * 4);
    int*    cur     = (int*)   alloc((size_t)NN * 4);
    int*    off     = (int*)   alloc((size_t)(NN + 1) * 4);
    int*    bsum    = (int*)   alloc(256 * 4);
    int*    bpre    = (int*)   alloc(256 * 4);
    int*    dcnt    = (int*)   alloc(DBINS * 4);
    int*    dcur    = (int*)   alloc(DBINS * 4);
    int*    dbase   = (int*)   alloc(DBINS * 4);
    int*    perm    = (int*)   alloc((size_t)NN * 4);
    int4*   ep      = (int4*)  alloc(((size_t)NE + 3*NN + 64) * 16);
    unsigned short* Wb1 = (unsigned short*)alloc(26 * 4096);
    unsigned short* WbS = (unsigned short*)alloc(2 * 4096);
    unsigned short* Wb2 = (unsigned short*)alloc(52 * 4096);
    float*  agg1    = (float*) alloc((size_t)NN * 64 * 4);
    float*  aggS    = (float*) alloc((size_t)NN * 64 * 4);
    unsigned short* h1bf = (unsigned short*)alloc((size_t)(NN + 1) * 64 * 2);
    unsigned short* xbf  = (unsigned short*)alloc((size_t)(NN + 1) * 32 * 2);
    float*  stats   = (float*) alloc(384 * 4);
    (void)ws_size; (void)in_sizes; (void)n_in; (void)out_size;

    float* out = (float*)d_out;

    k_zero<<<196, 256, 0, stream>>>(degi, cur, stats, dcnt, dcur,
                                    (unsigned*)(xbf + (size_t)NN * 32),
                                    (unsigned*)(h1bf + (size_t)NN * 64));
    k_hist<<<3125, 256, 0, stream>>>(dstp, degi);
    k_scan_block<<<49, 256, 0, stream>>>(degi, off, bsum);
    k_dhist<<<196, 256, 0, stream>>>(degi, dcnt);
    k_topscan<<<2, 256, 0, stream>>>(bsum, bpre, 49, dcnt, dbase);
    k_scan_add<<<196, 256, 0, stream>>>(off, bpre, degi);
    k_pscatter_pad<<<196, 256, 0, stream>>>(degi, dbase, dcur, perm, off, ep);
    k_scatter<<<3125, 256, 0, stream>>>(srcp, dstp, ea, off, cur, ep);

    k_prep<<<1643, 256, 0, stream>>>(x, xbf, w1, r1, Wb1, wsN, rs, WbS, w2, r2, Wb2);

    k_conv1s<<<3125, 512, 0, stream>>>(xbf, off, degi, ep, perm,
                                       Wb1, WbS, b1, bs, agg1, aggS);
    k_bnstats<<<256, 256, 0, stream>>>(agg1, stats);
    k_bn_elu<<<3125, 256, 0, stream>>>(agg1, stats, g1, be1, h1bf);

    k_conv2<<<3125, 512, 0, stream>>>(h1bf, off, degi, ep, perm,
                                      Wb2, b2, agg1);
    k_bnstats2<<<512, 256, 0, stream>>>(agg1, aggS, stats);
    k_bn_final<<<3125, 256, 0, stream>>>(agg1, stats + 128, g2, be2,
                                         aggS, stats + 256, gs, bes, out);
}

// Round 14
// 412.448 us; speedup vs baseline: 3.2576x; 3.2576x over previous
//
#include <hip/hip_runtime.h>

#define NN 50000
#define NE 800000
#define DBINS 1024

typedef __attribute__((ext_vector_type(8))) short bf16x8;
typedef __attribute__((ext_vector_type(4))) float f32x4;
typedef __attribute__((ext_vector_type(2))) float f32x2;

__device__ __forceinline__ unsigned short f2bf(float f) {
    union { float f; unsigned u; } v; v.f = f;
    unsigned r = v.u + 0x7FFFu + ((v.u >> 16) & 1u);
    return (unsigned short)(r >> 16);
}

// 32-bit-offset gathers (uniform 64-bit base + 32-bit voffset)
__device__ __forceinline__ int4 ld_ep2(const int4* ep, unsigned idx, int which) {
    return *(const int4*)((const char*)ep + (size_t)(idx * 32u + (unsigned)which * 16u));
}
__device__ __forceinline__ unsigned ld_xu(const unsigned* X, unsigned byteoff) {
    return *(const unsigned*)((const char*)X + (size_t)byteoff);
}

// dword of 2 packed bf16 (lo, hi) -> f32x2 {lo, hi}
__device__ __forceinline__ f32x2 unpack2(unsigned u) {
    union { unsigned u; float f; } a, b;
    a.u = u << 16;
    b.u = u & 0xFFFF0000u;
    return f32x2{a.f, b.f};
}

// ---- forced VOP3P packed-f32 with op_sel broadcasts (validated r3/r4) ----
__device__ __forceinline__ f32x2 pk_mul_hib(f32x2 w, f32x2 x) {
    f32x2 d;
    asm("v_pk_mul_f32 %0, %1, %2 op_sel:[1,0] op_sel_hi:[1,1]"
        : "=v"(d) : "v"(w), "v"(x));
    return d;
}
__device__ __forceinline__ void pk_fma_lob(f32x2& h, f32x2 w, f32x2 t) {
    asm("v_pk_fma_f32 %0, %1, %2, %0 op_sel:[0,0,0] op_sel_hi:[0,1,1]"
        : "+v"(h) : "v"(w), "v"(t));
}

// bf16 LDS A-fragment layout (16 nodes):
//   element (kstep kk, r = k&31, node m) at ushort index
//   kk*544 + (r>>3)*136 + m*8 + (r&7)
__device__ __forceinline__ int us_idx(int kk, int r, int m) {
    return kk*544 + (r >> 3)*136 + m*8 + (r & 7);
}

// packed hat-weight accumulate; weights preloaded per edge (bf16 pairs).
// Branch-free dense form: 25 pk_fma — register-resident (sparse-switch and
// MFMA-keeper variants both spilled; this is the verified floor).
template<bool HS>
__device__ __forceinline__ void edge_acc2(f32x2* h, f32x2& hs,
                                          const int4& pa, const int4& pb, f32x2 x) {
    f32x2 wxy[5];
    wxy[0] = unpack2((unsigned)pa.y);
    wxy[1] = unpack2((unsigned)pa.z);
    wxy[2] = unpack2((unsigned)pa.w);
    wxy[3] = unpack2((unsigned)pb.x);
    wxy[4] = unpack2((unsigned)pb.y);
    if (HS) hs += x;
#pragma unroll
    for (int r1 = 0; r1 < 5; ++r1) {
        f32x2 ty = pk_mul_hib(wxy[r1], x);
#pragma unroll
        for (int r0 = 0; r0 < 5; ++r0)
            pk_fma_lob(h[r1*5 + r0], wxy[r0], ty);
    }
}

__device__ __forceinline__ float eh_reduce(f32x2 v, int eh, int stride) {
    float mine  = eh ? v.y : v.x;
    float other = eh ? v.x : v.y;
    return mine + __shfl_xor(other, stride);
}

// ---------------- setup kernels ----------------
__global__ __launch_bounds__(256) void k_zero(int* degi, int* cur, float* stats,
                                              int* dcnt, int* dcur,
                                              unsigned* xz, unsigned* hz) {
    int i = blockIdx.x*256 + threadIdx.x;
    int stride = gridDim.x*256;
    for (int j = i; j < NN; j += stride) { degi[j] = 0; cur[j] = 0; }
    if (i < 384) stats[i] = 0.f;
    if (i < DBINS) { dcnt[i] = 0; dcur[i] = 0; }
    if (i < 16) xz[i] = 0u;
    if (i < 32) hz[i] = 0u;
}

__global__ __launch_bounds__(256) void k_hist(const int* __restrict__ dst, int* degi) {
    int e = blockIdx.x*256 + threadIdx.x;
    if (e < NE) atomicAdd(&degi[dst[e]], 1);
}

// fused: blocks 0..48 = scan of CEIL4(deg) -> padded offsets;
//        blocks 49..244 = 1024-bin LDS-staged degree histogram.
__global__ __launch_bounds__(256) void k_sbdh(const int* __restrict__ degi,
                                              int* off, int* bsum, int* dcnt) {
    __shared__ int lh[DBINS];
    int t = threadIdx.x;
    if (blockIdx.x < 49) {
        int base = blockIdx.x * 1024;
        int v[4]; int s = 0;
#pragma unroll
        for (int j = 0; j < 4; j++) {
            int idx = base + t*4 + j;
            v[j] = (idx < NN) ? ((degi[idx] + 3) & ~3) : 0;
            s += v[j];
        }
        lh[t] = s; __syncthreads();
        for (int ofs = 1; ofs < 256; ofs <<= 1) {
            int x = (t >= ofs) ? lh[t - ofs] : 0;
            __syncthreads();
            lh[t] += x;
            __syncthreads();
        }
        int ex = lh[t] - s;
#pragma unroll
        for (int j = 0; j < 4; j++) {
            int idx = base + t*4 + j;
            if (idx < NN) off[idx] = ex;
            ex += v[j];
        }
        if (t == 255) bsum[blockIdx.x] = lh[255];
    } else {
#pragma unroll
        for (int j = 0; j < DBINS/256; ++j) lh[t + 256*j] = 0;
        __syncthreads();
        int n = (blockIdx.x - 49)*256 + t;
        if (n < NN) atomicAdd(&lh[min(degi[n], DBINS-1)], 1);
        __syncthreads();
#pragma unroll
        for (int j = 0; j < DBINS/256; ++j) {
            int b = t + 256*j;
            if (lh[b]) atomicAdd(&dcnt[b], lh[b]);
        }
    }
}

// fused: block 0 = top-level scan of bsum; block 1 = 1024-bin degree scan
__global__ __launch_bounds__(256) void k_topscan(const int* __restrict__ bsum,
                                                 int* bpre, int nb,
                                                 const int* __restrict__ dcnt,
                                                 int* dbase) {
    __shared__ int sh[256];
    int t = threadIdx.x;
    if (blockIdx.x == 0) {
        int s = (t < nb) ? bsum[t] : 0;
        sh[t] = s; __syncthreads();
        for (int ofs = 1; ofs < 256; ofs <<= 1) {
            int x = (t >= ofs) ? sh[t - ofs] : 0;
            __syncthreads();
            sh[t] += x;
            __syncthreads();
        }
        if (t < nb) bpre[t] = sh[t] - s;
    } else {
        int v[4]; int s = 0;
#pragma unroll
        for (int j = 0; j < 4; j++) { v[j] = dcnt[t*4 + j]; s += v[j]; }
        sh[t] = s; __syncthreads();
        for (int ofs = 1; ofs < 256; ofs <<= 1) {
            int x = (t >= ofs) ? sh[t - ofs] : 0;
            __syncthreads();
            sh[t] += x;
            __syncthreads();
        }
        int ex = sh[t] - s;
#pragma unroll
        for (int j = 0; j < 4; j++) { dbase[t*4 + j] = ex; ex += v[j]; }
    }
}

__global__ __launch_bounds__(256) void k_scan_add(int* off, const int* __restrict__ bpre,
                                                  const int* __restrict__ degi) {
    int i = blockIdx.x*256 + threadIdx.x;
    if (i < NN) {
        int v = off[i] + bpre[i >> 10];
        off[i] = v;
        if (i == NN - 1) off[NN] = v + ((degi[i] + 3) & ~3);
    }
}

// fused: counting-sort scatter (LDS-staged) + pad fill
__global__ __launch_bounds__(256) void k_pscatter_pad(const int* __restrict__ degi,
                                                      const int* __restrict__ dbase,
                                                      int* dcur, int* perm,
                                                      const int* __restrict__ off,
                                                      int4* __restrict__ ep) {
    __shared__ int lh[DBINS];
    __shared__ int lb[DBINS];
    int t = threadIdx.x;
#pragma unroll
    for (int j = 0; j < DBINS/256; ++j) lh[t + 256*j] = 0;
    __syncthreads();
    int n = blockIdx.x*256 + t;
    int d = 0, lr = 0;
    bool act = (n < NN);
    if (act) {
        d = min(degi[n], DBINS-1);
        lr = atomicAdd(&lh[d], 1);
    }
    __syncthreads();
#pragma unroll
    for (int j = 0; j < DBINS/256; ++j) {
        int b = t + 256*j;
        int c = lh[b];
        lb[b] = c ? atomicAdd(&dcur[b], c) : 0;
    }
    __syncthreads();
    if (act) {
        perm[dbase[d] + lb[d] + lr] = n;
        int base = off[n] + degi[n];
        int end  = off[n + 1];
        for (int p = base; p < end; ++p) {
            ep[2*p]     = make_int4(NN, 0, 0, 0);
            ep[2*p + 1] = make_int4(0, 0, 0, 0);
        }
    }
}

__device__ __forceinline__ void wprep_body(int tid, const float* W, const float* root,
                                           int KTC, unsigned short* Wb) {
    int lane = tid & 63, cot = (tid >> 6) & 3, kk = tid >> 8;
    int co = 16*cot + (lane & 15);
    int kbase = kk*32 + ((lane >> 4) * 8);
    union { unsigned short s[8]; uint4 v; } u;
#pragma unroll
    for (int j = 0; j < 8; j++) {
        int k = kbase + j;
        float val = (k < KTC) ? W[(size_t)k*64 + co] : root[(size_t)(k - KTC)*64 + co];
        u.s[j] = f2bf(val);
    }
    *(uint4*)(Wb + (size_t)tid * 8) = u.v;
}

// fused: blocks 0..3124 edge scatter (dense weight records);
//        blocks 3125..4687 x->bf16; 4688..4713 Wb1; 4714..4715 WbS; rest Wb2.
__global__ __launch_bounds__(256) void k_scatter_prep(
        const int* __restrict__ src, const int* __restrict__ dst,
        const float* __restrict__ ea, const int* __restrict__ off, int* cur,
        int4* __restrict__ ep,
        const float* __restrict__ x, unsigned short* __restrict__ xb,
        const float* __restrict__ w1, const float* __restrict__ r1,
        unsigned short* Wb1,
        const float* __restrict__ wsN, const float* __restrict__ rs,
        unsigned short* WbS,
        const float* __restrict__ w2, const float* __restrict__ r2,
        unsigned short* Wb2) {
    int b = blockIdx.x, t = threadIdx.x;
    if (b < 3125) {
        int e = b*256 + t;
        if (e >= NE) return;
        int d = dst[e];
        int p = off[d] + atomicAdd(&cur[d], 1);
        float v0 = ea[2*e]     * 4.f;
        float v1 = ea[2*e + 1] * 4.f;
        unsigned w[5];
#pragma unroll
        for (int r = 0; r < 5; ++r) {
            float wx = fmaxf(1.f - fabsf(v0 - (float)r), 0.f);
            float wy = fmaxf(1.f - fabsf(v1 - (float)r), 0.f);
            w[r] = (unsigned)f2bf(wx) | ((unsigned)f2bf(wy) << 16);
        }
        ep[2*p]     = make_int4(src[e], (int)w[0], (int)w[1], (int)w[2]);
        ep[2*p + 1] = make_int4((int)w[3], (int)w[4], 0, 0);
    } else if (b < 3125 + 1563) {
        int i = (b - 3125)*256 + t;
        if (i >= NN*8) return;
        float4 v = ((const float4*)x)[i];
        uint2 pk;
        pk.x = (unsigned)f2bf(v.x) | ((unsigned)f2bf(v.y) << 16);
        pk.y = (unsigned)f2bf(v.z) | ((unsigned)f2bf(v.w) << 16);
        ((uint2*)xb)[i] = pk;
    } else if (b < 3125 + 1589) {
        wprep_body((b - 3125 - 1563)*256 + t, w1, r1, 800, Wb1);
    } else if (b < 3125 + 1591) {
        wprep_body((b - 3125 - 1589)*256 + t, wsN, rs, 32, WbS);
    } else {
        wprep_body((b - 3125 - 1591)*256 + t, w2, r2, 1600, Wb2);
    }
}

// ---------------- conv1 + convS fused: 16 nodes/block ----------------
// LPT order: heaviest (highest-degree) blocks first (perm is degree-ascending).
__global__ __launch_bounds__(512, 4) void k_conv1s(
        const unsigned* __restrict__ Xbf,        // [NN+1][16] dwords (32 bf16 ch)
        const int* __restrict__ off,
        const int* __restrict__ degi,
        const int4* __restrict__ ep,
        const int* __restrict__ perm,
        const unsigned short* __restrict__ Wb1,
        const unsigned short* __restrict__ WbS,
        const float* __restrict__ b1,
        const float* __restrict__ bs,
        float* __restrict__ agg1,
        float* __restrict__ aggS) {
    __shared__ __align__(16) unsigned short hb[28*544];  // 30.5 KB
    const int t = threadIdx.x;
    const int g = t >> 5;
    const int q = t & 31;
    const int chp = q & 15;
    const int eh = q >> 4;
    const int n0 = NN - 16 - blockIdx.x * 16;   // LPT order
    const int n = perm[n0 + g];

    f32x2 h[25], hs = {0.f, 0.f};
#pragma unroll
    for (int i = 0; i < 25; ++i) h[i] = f32x2{0.f, 0.f};

    const int ebeg = off[n], eend = off[n + 1];
    const float rdeg = 1.f / (float)max(degi[n], 1);

    for (int i = ebeg; i < eend; i += 4) {
        const unsigned i0 = (unsigned)(i + eh), i1 = (unsigned)(i + 2 + eh);
        int4 a0 = ld_ep2(ep, i0, 0), b0 = ld_ep2(ep, i0, 1);
        int4 a1 = ld_ep2(ep, i1, 0), b1 = ld_ep2(ep, i1, 1);
        unsigned u0 = ld_xu(Xbf, (unsigned)a0.x * 64u + (unsigned)chp * 4u);
        unsigned u1 = ld_xu(Xbf, (unsigned)a1.x * 64u + (unsigned)chp * 4u);
        edge_acc2<true>(h, hs, a0, b0, unpack2(u0));
        edge_acc2<true>(h, hs, a1, b1, unpack2(u1));
    }

    const int c = 2*chp + eh;
    const int bw = us_idx(0, c, g);
#pragma unroll
    for (int wi = 0; wi < 25; ++wi)
        hb[wi*544 + bw] = f2bf(eh_reduce(h[wi], eh, 16) * rdeg);
    hb[26*544 + bw] = f2bf(eh_reduce(hs, eh, 16) * rdeg);
    {
        unsigned ux = Xbf[(unsigned)n * 16u + (unsigned)chp];
        unsigned short xb = eh ? (unsigned short)(ux >> 16)
                               : (unsigned short)(ux & 0xFFFFu);
        hb[25*544 + bw] = xb;
        hb[27*544 + bw] = xb;
    }
    __syncthreads();

    const int lane = t & 63, w = t >> 6;
    const int m = lane & 15, qq = lane >> 4;
    const int co = (w & 3)*16 + m;
    const int4 pn = ((const int4*)perm)[(n0 >> 2) + qq];
    const int prow[4] = {pn.x, pn.y, pn.z, pn.w};
    if (w < 4) {
        f32x4 acc = {0.f, 0.f, 0.f, 0.f};
        for (int kk = 0; kk < 26; ++kk) {
            bf16x8 av = *(const bf16x8*)&hb[kk*544 + qq*136 + m*8];
            bf16x8 bv = *(const bf16x8*)(Wb1 + (size_t)((kk*4 + w)*64 + lane) * 8);
            acc = __builtin_amdgcn_mfma_f32_16x16x32_bf16(av, bv, acc, 0, 0, 0);
        }
        const float bb = b1[co];
#pragma unroll
        for (int r = 0; r < 4; ++r)
            agg1[(size_t)prow[r]*64 + co] = acc[r] + bb;
    } else {
        f32x4 accs = {0.f, 0.f, 0.f, 0.f};
#pragma unroll
        for (int s = 0; s < 2; ++s) {
            bf16x8 av = *(const bf16x8*)&hb[(26 + s)*544 + qq*136 + m*8];
            bf16x8 bv = *(const bf16x8*)(WbS + (size_t)((s*4 + (w & 3))*64 + lane) * 8);
            accs = __builtin_amdgcn_mfma_f32_16x16x32_bf16(av, bv, accs, 0, 0, 0);
        }
        const float bb = bs[co];
#pragma unroll
        for (int r = 0; r < 4; ++r)
            aggS[(size_t)prow[r]*64 + co] = accs[r] + bb;
    }
}

// ---------------- conv2: 16 nodes/block, K-split phase B ----------------
// 512 threads, 8 waves. Half-wave (t>>5) owns one node; lane chp = channel
// pair (c0=2chp, c1=2chp+1) -> no eh_reduce, dword dumps (conflict-free).
// LDS holds 26 of 52 K-steps (27.6 KB): dump wi 0..12 -> MFMA -> barrier ->
// dump wi 13..24 + x -> MFMA. LPT block order.
__global__ __launch_bounds__(512, 6) void k_conv2(
        const unsigned* __restrict__ Xbf,        // h1 bf16: [NN+1][32] dwords
        const int* __restrict__ off,
        const int* __restrict__ degi,
        const int4* __restrict__ ep,
        const int* __restrict__ perm,
        const unsigned short* __restrict__ Wb2,
        const float* __restrict__ b2,
        float* __restrict__ agg) {
    __shared__ __align__(16) unsigned short hb[26*544];  // 27.6 KB
    unsigned* hb32 = (unsigned*)hb;
    const int t = threadIdx.x, lane = t & 63, w = t >> 6;
    const int n0 = NN - 16 - blockIdx.x * 16;   // LPT order
    const int g = t >> 5;            // node slot 0..15 (one per half-wave)
    const int chp = t & 31;          // channel pair
    const int n = perm[n0 + g];

    f32x2 h[25];
#pragma unroll
    for (int i = 0; i < 25; ++i) h[i] = f32x2{0.f, 0.f};

    const int ebeg = off[n], eend = off[n + 1];
    const float rdeg = 1.f / (float)max(degi[n], 1);

    for (int i = ebeg; i < eend; i += 2) {
        int4 a0 = ld_ep2(ep, (unsigned)i, 0),       b0 = ld_ep2(ep, (unsigned)i, 1);
        int4 a1 = ld_ep2(ep, (unsigned)(i+1), 0),   b1 = ld_ep2(ep, (unsigned)(i+1), 1);
        unsigned u0 = ld_xu(Xbf, (unsigned)a0.x * 128u + (unsigned)chp * 4u);
        unsigned u1 = ld_xu(Xbf, (unsigned)a1.x * 128u + (unsigned)chp * 4u);
        f32x2 dummy = {0.f, 0.f};
        edge_acc2<false>(h, dummy, a0, b0, unpack2(u0));
        edge_acc2<false>(h, dummy, a1, b1, unpack2(u1));
    }

    // dword dump address: channels 2chp,2chp+1 are adjacent ushorts
    const int kh = chp >> 4;                 // k-row parity (c>>5)
    const int r0 = (2*chp) & 31;
    const int dw = us_idx(0, r0, g) >> 1;    // dword index within a kk-row
    // ---- part 1: wi 0..12 -> kk = 2*wi + kh (0..25) ----
#pragma unroll
    for (int wi = 0; wi <= 12; ++wi) {
        unsigned pk = (unsigned)f2bf(h[wi].x * rdeg)
                    | ((unsigned)f2bf(h[wi].y * rdeg) << 16);
        hb32[(unsigned)(2*wi + kh)*272u + dw] = pk;
    }
    __syncthreads();

    const int m = lane & 15, qq = lane >> 4;
    f32x4 acc = {0.f, 0.f, 0.f, 0.f};
    if (w < 4) {
        for (int kk = 0; kk < 26; ++kk) {
            bf16x8 av = *(const bf16x8*)&hb[kk*544 + qq*136 + m*8];
            bf16x8 bv = *(const bf16x8*)(Wb2 + (size_t)((kk*4 + w)*64 + lane) * 8);
            acc = __builtin_amdgcn_mfma_f32_16x16x32_bf16(av, bv, acc, 0, 0, 0);
        }
    }
    __syncthreads();

    // ---- part 2: wi 13..24 -> local kk = 2*wi + kh - 26 (0..23); x -> 24+kh
#pragma unroll
    for (int wi = 13; wi < 25; ++wi) {
        unsigned pk = (unsigned)f2bf(h[wi].x * rdeg)
                    | ((unsigned)f2bf(h[wi].y * rdeg) << 16);
        hb32[(unsigned)(2*wi + kh - 26)*272u + dw] = pk;
    }
    hb32[(unsigned)(24 + kh)*272u + dw] = Xbf[(unsigned)n * 32u + (unsigned)chp];
    __syncthreads();

    if (w >= 4) return;
    for (int kk = 0; kk < 26; ++kk) {
        bf16x8 av = *(const bf16x8*)&hb[kk*544 + qq*136 + m*8];
        bf16x8 bv = *(const bf16x8*)(Wb2 + (size_t)(((kk + 26)*4 + w)*64 + lane) * 8);
        acc = __builtin_amdgcn_mfma_f32_16x16x32_bf16(av, bv, acc, 0, 0, 0);
    }
    const int4 pn = ((const int4*)perm)[(n0 >> 2) + qq];
    const int prow[4] = {pn.x, pn.y, pn.z, pn.w};
    const int co = w*16 + m;
    const float bb = b2[co];
#pragma unroll
    for (int rr = 0; rr < 4; ++rr)
        agg[(size_t)prow[rr]*64 + co] = acc[rr] + bb;
}

// ---------------- batch norm ----------------
__global__ __launch_bounds__(256) void k_bnstats(const float* __restrict__ agg, float* stats) {
    __shared__ float sh0[256], sh1[256];
    int t = threadIdx.x;
    float s = 0.f, ss = 0.f;
    int stride = gridDim.x * 256;
    for (int i = blockIdx.x*256 + t; i < NN*64; i += stride) {
        float v = agg[i];
        s += v; ss += v*v;
    }
    sh0[t] = s; sh1[t] = ss;
    __syncthreads();
    if (t < 64) {
        float a = sh0[t] + sh0[t+64] + sh0[t+128] + sh0[t+192];
        float b = sh1[t] + sh1[t+64] + sh1[t+128] + sh1[t+192];
        atomicAdd(&stats[t], a);
        atomicAdd(&stats[64 + t], b);
    }
}

// fused: stats for agg1 (blocks 0..255 -> st2) and aggS (blocks 256..511 -> sts)
__global__ __launch_bounds__(256) void k_bnstats2(const float* __restrict__ a1,
                                                  const float* __restrict__ as,
                                                  float* stats) {
    __shared__ float sh0[256], sh1[256];
    int t = threadIdx.x;
    const float* src = (blockIdx.x < 256) ? a1 : as;
    float* dst = (blockIdx.x < 256) ? (stats + 128) : (stats + 256);
    int bid = (blockIdx.x < 256) ? blockIdx.x : blockIdx.x - 256;
    float s = 0.f, ss = 0.f;
    for (int i = bid*256 + t; i < NN*64; i += 256*256) {
        float v = src[i];
        s += v; ss += v*v;
    }
    sh0[t] = s; sh1[t] = ss;
    __syncthreads();
    if (t < 64) {
        float a = sh0[t] + sh0[t+64] + sh0[t+128] + sh0[t+192];
        float b = sh1[t] + sh1[t+64] + sh1[t+128] + sh1[t+192];
        atomicAdd(&dst[t], a);
        atomicAdd(&dst[64 + t], b);
    }
}

__device__ __forceinline__ float eluf(float u) { return u > 0.f ? u : expm1f(u); }

__global__ __launch_bounds__(256) void k_bn_elu(const float* __restrict__ agg,
                                                const float* __restrict__ stats,
                                                const float* __restrict__ gamma,
                                                const float* __restrict__ beta,
                                                unsigned short* __restrict__ outb) {
    int i = blockIdx.x*256 + threadIdx.x;
    if (i >= NN*16) return;
    float4 v = ((const float4*)agg)[i];
    float r[4] = {v.x, v.y, v.z, v.w};
    int c0 = (i << 2) & 63;
#pragma unroll
    for (int j = 0; j < 4; j++) {
        int c = c0 + j;
        float mu = stats[c] * (1.f/NN);
        float var = stats[64 + c] * (1.f/NN) - mu*mu;
        float sc = gamma[c] * rsqrtf(fmaxf(var, 0.f) + 1e-5f);
        r[j] = eluf((r[j] - mu)*sc + beta[c]);
    }
    uint2 pk;
    pk.x = (unsigned)f2bf(r[0]) | ((unsigned)f2bf(r[1]) << 16);
    pk.y = (unsigned)f2bf(r[2]) | ((unsigned)f2bf(r[3]) << 16);
    ((uint2*)outb)[i] = pk;
}

__global__ __launch_bounds__(256) void k_bn_final(const float* __restrict__ a2,
                                                  const float* __restrict__ st2,
                                                  const float* __restrict__ g2,
                                                  const float* __restrict__ be2,
                                                  const float* __restrict__ as,
                                                  const float* __restrict__ sts,
                                                  const float* __restrict__ gs,
                                                  const float* __restrict__ bes,
                                                  float* __restrict__ out) {
    int i = blockIdx.x*256 + threadIdx.x;
    if (i >= NN*16) return;
    float4 v2 = ((const float4*)a2)[i];
    float4 vs = ((const float4*)as)[i];
    float r2v[4] = {v2.x, v2.y, v2.z, v2.w};
    float rsv[4] = {vs.x, vs.y, vs.z, vs.w};
    float o[4];
    int c0 = (i << 2) & 63;
#pragma unroll
    for (int j = 0; j < 4; j++) {
        int c = c0 + j;
        float mu2 = st2[c] * (1.f/NN);
        float var2 = st2[64 + c] * (1.f/NN) - mu2*mu2;
        float sc2 = g2[c] * rsqrtf(fmaxf(var2, 0.f) + 1e-5f);
        float mus = sts[c] * (1.f/NN);
        float vars = sts[64 + c] * (1.f/NN) - mus*mus;
        float scs = gs[c] * rsqrtf(fmaxf(vars, 0.f) + 1e-5f);
        float u = (r2v[j] - mu2)*sc2 + be2[c] + (rsv[j] - mus)*scs + bes[c];
        o[j] = eluf(u);
    }
    ((float4*)out)[i] = make_float4(o[0], o[1], o[2], o[3]);
}

extern "C" void kernel_launch(void* const* d_in, const int* in_sizes, int n_in,
                              void* d_out, int out_size, void* d_ws, size_t ws_size,
                              hipStream_t stream) {
    const float* x   = (const float*)d_in[0];
    const int*   ei  = (const int*)d_in[1];
    const float* ea  = (const float*)d_in[2];
    const float* w1  = (const float*)d_in[3];
    const float* r1  = (const float*)d_in[4];
    const float* b1  = (const float*)d_in[5];
    const float* g1  = (const float*)d_in[6];
    const float* be1 = (const float*)d_in[7];
    const float* w2  = (const float*)d_in[8];
    const float* r2  = (const float*)d_in[9];
    const float* b2  = (const float*)d_in[10];
    const float* g2  = (const float*)d_in[11];
    const float* be2 = (const float*)d_in[12];
    const float* wsN = (const float*)d_in[13];
    const float* rs  = (const float*)d_in[14];
    const float* bs  = (const float*)d_in[15];
    const float* gs  = (const float*)d_in[16];
    const float* bes = (const float*)d_in[17];
    const int* srcp = ei;
    const int* dstp = ei + NE;

    char* wsb = (char*)d_ws;
    size_t o = 0;
    auto alloc = [&](size_t bytes) -> char* {
        char* p = wsb + o;
        o += (bytes + 255) & ~(size_t)255;
        return p;
    };
    int*    degi    = (int*)   alloc((size_t)NN * 4);
    int*    cur     = (int*)   alloc((size_t)NN * 4);
    int*    off     = (int*)   alloc((size_t)(NN + 1) * 4);
    int*    bsum    = (int*)   alloc(256 * 4);
    int*    bpre    = (int*)   alloc(256 * 4);
    int*    dcnt    = (int*)   alloc(DBINS * 4);
    int*    dcur    = (int*)   alloc(DBINS * 4);
    int*    dbase   = (int*)   alloc(DBINS * 4);
    int*    perm    = (int*)   alloc((size_t)NN * 4);
    int4*   ep      = (int4*)  alloc(((size_t)NE + 3*NN + 64) * 32);  // padded
    unsigned short* Wb1 = (unsigned short*)alloc(26 * 4096);
    unsigned short* WbS = (unsigned short*)alloc(2 * 4096);
    unsigned short* Wb2 = (unsigned short*)alloc(52 * 4096);
    float*  agg1    = (float*) alloc((size_t)NN * 64 * 4);
    float*  aggS    = (float*) alloc((size_t)NN * 64 * 4);
    unsigned short* h1bf = (unsigned short*)alloc((size_t)(NN + 1) * 64 * 2);
    unsigned short* xbf  = (unsigned short*)alloc((size_t)(NN + 1) * 32 * 2);
    float*  stats   = (float*) alloc(384 * 4);
    (void)ws_size; (void)in_sizes; (void)n_in; (void)out_size;

    float* out = (float*)d_out;

    k_zero<<<196, 256, 0, stream>>>(degi, cur, stats, dcnt, dcur,
                                    (unsigned*)(xbf + (size_t)NN * 32),
                                    (unsigned*)(h1bf + (size_t)NN * 64));
    k_hist<<<3125, 256, 0, stream>>>(dstp, degi);
    k_sbdh<<<245, 256, 0, stream>>>(degi, off, bsum, dcnt);
    k_topscan<<<2, 256, 0, stream>>>(bsum, bpre, 49, dcnt, dbase);
    k_scan_add<<<196, 256, 0, stream>>>(off, bpre, degi);
    k_pscatter_pad<<<196, 256, 0, stream>>>(degi, dbase, dcur, perm, off, ep);
    k_scatter_prep<<<4768, 256, 0, stream>>>(srcp, dstp, ea, off, cur, ep,
                                             x, xbf, w1, r1, Wb1,
                                             wsN, rs, WbS, w2, r2, Wb2);

    k_conv1s<<<3125, 512, 0, stream>>>((const unsigned*)xbf, off, degi, ep, perm,
                                       Wb1, WbS, b1, bs, agg1, aggS);
    k_bnstats<<<256, 256, 0, stream>>>(agg1, stats);
    k_bn_elu<<<3125, 256, 0, stream>>>(agg1, stats, g1, be1, h1bf);

    k_conv2<<<3125, 512, 0, stream>>>((const unsigned*)h1bf, off, degi, ep, perm,
                                      Wb2, b2, agg1);
    k_bnstats2<<<512, 256, 0, stream>>>(agg1, aggS, stats);
    k_bn_final<<<3125, 256, 0, stream>>>(agg1, stats + 128, g2, be2,
                                         aggS, stats + 256, gs, bes, out);
}